// Round 3
// baseline (7678.924 us; speedup 1.0000x reference)
//
#include <hip/hip_runtime.h>

#define DEV __device__ __forceinline__

using short8 = __attribute__((ext_vector_type(8))) short;
using f32x4  = __attribute__((ext_vector_type(4))) float;

DEV float b2f(short s) {
  union { unsigned u; float f; } c;
  c.u = ((unsigned)(unsigned short)s) << 16;
  return c.f;
}
DEV short f2b(float f) {
  union { float f; unsigned u; } c; c.f = f;
  unsigned u = c.u + 0x7fffu + ((c.u >> 16) & 1u);
  return (short)(u >> 16);
}
// async global->LDS, 16B per lane. LDS dest = uniform base + lane*16.
DEV void async_ld16(const void* g, void* lds) {
  __builtin_amdgcn_global_load_lds(
      (const __attribute__((address_space(1))) void*)(unsigned long long)g,
      (__attribute__((address_space(3))) void*)(unsigned)(unsigned long long)lds,
      16, 0, 0);
}

// ---------------- init: slots + hx[0] ----------------
__global__ void k_init(int* slots, short* hx) {
  int i = blockIdx.x * 256 + threadIdx.x;
  if (i < 64) slots[i] = 0;
  if (i < 8192) { hx[i] = 0; hx[4202496 + i] = 0; }
}

// ---------------- fp32 -> bf16 convert, 4 weight tensors in one dispatch ----------------
__global__ __launch_bounds__(256) void k_cvt4(const float* __restrict__ a, const float* __restrict__ b,
                                              const float* __restrict__ c, const float* __restrict__ d,
                                              short* __restrict__ oa, short* __restrict__ ob,
                                              short* __restrict__ oc, short* __restrict__ od) {
  int blk = blockIdx.x;
  const float* in; short* out; int base;
  if (blk < 384)      { in = a; out = oa; base = blk; }
  else if (blk < 768) { in = b; out = ob; base = blk - 384; }
  else if (blk < 960) { in = c; out = oc; base = blk - 768; }
  else                { in = d; out = od; base = blk - 960; }
  int i = base * 256 + threadIdx.x;
  f32x4 v = *(const f32x4*)(in + (size_t)i * 4);
  short4 o;
#pragma unroll
  for (int j = 0; j < 4; j++) ((short*)&o)[j] = f2b(v[j]);
  *(short4*)(out + (size_t)i * 4) = o;
}

// ---------------- fp32 (R,C) -> bf16 (C,R) transpose+convert, 4 matrices merged ----------------
__global__ __launch_bounds__(256) void k_transcvt(const float* __restrict__ in0,
                                                  short* __restrict__ out0, int R, int C) {
  __shared__ float tile[32][33];
  int mat = blockIdx.x >> 10;                 // 1024 blocks per matrix
  const float* in = in0 + (size_t)mat * 1048576;
  short* out = out0 + (size_t)mat * 1048576;
  int blk = blockIdx.x & 1023;
  int ct = C >> 5;
  int bc = blk % ct, br = blk / ct;
  int r0 = br << 5, c0 = bc << 5;
  for (int i = threadIdx.x; i < 1024; i += 256) {
    int r = i >> 5, c = i & 31;
    tile[r][c] = in[(size_t)(r0 + r) * C + c0 + c];
  }
  __syncthreads();
  for (int i = threadIdx.x; i < 1024; i += 256) {
    int c = i >> 5, r = i & 31;
    out[(size_t)(c0 + c) * R + r0 + r] = f2b(tile[r][c]);
  }
}

// ---------------- embed + positional encoding (fp32 W -> bf16 h0) ----------------
__global__ __launch_bounds__(256) void k_embed(const int* __restrict__ x,
                                               const float* __restrict__ W,
                                               short* __restrict__ h0) {
  int flat = blockIdx.x * 256 + threadIdx.x;   // 0 .. 1048575 (B*T*E/8)
  int row  = flat >> 6;                        // b*T + t
  int e0   = (flat & 63) << 3;
  int tok  = x[row];
  int t    = row & 511;
  const float* wp = W + (size_t)tok * 512 + e0;
  float v[8];
  *(f32x4*)v       = *(const f32x4*)(wp);
  *(f32x4*)(v + 4) = *(const f32x4*)(wp + 4);
  short8 o;
#pragma unroll
  for (int i = 0; i < 8; i += 2) {
    float f = expf(-9.210340371976184f * (float)(e0 + i) * (1.f / 512.f));
    float ang = (float)t * f;
    o[i]     = f2b(v[i]     + sinf(ang));
    o[i + 1] = f2b(v[i + 1] + cosf(ang));
  }
  *(short8*)(h0 + (size_t)flat * 8) = o;
}

// ---------------- 128x128 MFMA GEMM, A(M,K) bf16 * B(N,K) bf16 ----------------
// LDS tiles in MFMA fragment order: chunk c = kb*8 + mb holds a 16x32 block as
// 64 lanes x 16B -> ds_read_b128 at lane*16 conflict-free.
// MODE 0: fp32 out + fp32 bias.  MODE 1: bf16 out + fp32 bias + relu.
template <int MODE>
__global__ __launch_bounds__(256) void k_gemm(const short* __restrict__ A,
    const short* __restrict__ B, const float* __restrict__ bias,
    float* __restrict__ Cf, short* __restrict__ Cb, int M, int N, int K) {
  __shared__ short smA[8192];
  __shared__ short smB[8192];
  const int tid = threadIdx.x, lane = tid & 63, wave = tid >> 6;
  const int m15 = lane & 15, q8 = (lane >> 4) << 3;
  const int tn = N >> 7;
  const int bm = blockIdx.x / tn, bn = blockIdx.x % tn;
  const int wm = wave & 1, wn = wave >> 1;
  const f32x4 z4 = {0.f, 0.f, 0.f, 0.f};
  f32x4 acc[4][4];
#pragma unroll
  for (int i = 0; i < 4; i++)
#pragma unroll
    for (int j = 0; j < 4; j++) acc[i][j] = z4;

  for (int k0 = 0; k0 < K; k0 += 64) {
#pragma unroll
    for (int is = 0; is < 4; is++) {
      int c = is * 4 + wave;
      int mb = c & 7, kb = c >> 3;
      async_ld16(A + (size_t)(bm * 128 + mb * 16 + m15) * K + k0 + kb * 32 + q8, smA + c * 512);
      async_ld16(B + (size_t)(bn * 128 + mb * 16 + m15) * K + k0 + kb * 32 + q8, smB + c * 512);
    }
    __syncthreads();
#pragma unroll
    for (int kk = 0; kk < 2; kk++) {
      short8 af[4], bf[4];
#pragma unroll
      for (int i = 0; i < 4; i++)
        af[i] = *(const short8*)(smA + (kk * 8 + wm * 4 + i) * 512 + lane * 8);
#pragma unroll
      for (int j = 0; j < 4; j++)
        bf[j] = *(const short8*)(smB + (kk * 8 + wn * 4 + j) * 512 + lane * 8);
#pragma unroll
      for (int i = 0; i < 4; i++)
#pragma unroll
        for (int j = 0; j < 4; j++)
          acc[i][j] = __builtin_amdgcn_mfma_f32_16x16x32_bf16(af[i], bf[j], acc[i][j], 0, 0, 0);
    }
    __syncthreads();
  }
#pragma unroll
  for (int j = 0; j < 4; j++) {
    int col = bn * 128 + wn * 64 + j * 16 + m15;
    float bv = bias[col];
#pragma unroll
    for (int i = 0; i < 4; i++) {
      int row0 = bm * 128 + wm * 64 + i * 16 + ((lane >> 4) << 2);
#pragma unroll
      for (int r = 0; r < 4; r++) {
        float v = acc[i][j][r] + bv;
        size_t off = (size_t)(row0 + r) * N + col;
        if (MODE == 0) Cf[off] = v;
        else { if (v < 0.f) v = 0.f; Cb[off] = f2b(v); }
      }
    }
  }
}

// ---------------- bidirectional GRU recurrence, barrier-free ----------------
// grid=64; active blocks: (b&7)<2 -> XCD-pinned via %8 round-robin heuristic.
// dir d = b&7, slice w = b>>3. Block owns h-cols [32w,32w+32).
// Wave v: m-tile v&1 (16 batch rows), 16 h-cols at w*32+(v>>1)*16.
// w_hh B-fragments entirely in registers (24 x short8 = 96 VGPR). No LDS, no
// __syncthreads. Per-wave release slots (32/dir); readers 64-lane ballot-spin.
// Gates computed in MFMA C-layout in-lane; h_prev lives in registers.
__global__ __launch_bounds__(256, 1) void k_gru(
    const short* __restrict__ whh_f, const short* __restrict__ whh_b,
    const float* __restrict__ bhh_f, const float* __restrict__ bhh_b,
    const float* __restrict__ gi_f, const float* __restrict__ gi_b,
    short* __restrict__ hx, int* __restrict__ slots,
    short* __restrict__ hcat16, float* __restrict__ hres) {
  const int b = blockIdx.x;
  const int xcd = b & 7;
  if (xcd >= 2) return;
  const int d = xcd, w = b >> 3;
  const int tid = threadIdx.x, lane = tid & 63, wave = tid >> 6;
  const int m15 = lane & 15, quad = lane >> 4, q8 = quad * 8;
  const int mt = wave & 1, sub = wave >> 1;
  const int hc = w * 32 + sub * 16 + m15;         // this lane's h column
  const short* whh = d ? whh_b : whh_f;
  const float* bhh = d ? bhh_b : bhh_f;
  const float* gi  = d ? gi_b : gi_f;
  short* myhx = hx + (size_t)d * 4202496;
  int* S = slots + d * 32;
  const int slot_id = w * 4 + wave;

  // B fragments: gate g (r,z,n), k-block kb -> w_hh[g*256+hc][kb*32+q8 ..+8]
  short8 Bf[3][8];
#pragma unroll
  for (int g = 0; g < 3; g++)
#pragma unroll
    for (int kb = 0; kb < 8; kb++)
      Bf[g][kb] = *(const short8*)(whh + (size_t)(g * 256 + hc) * 256 + kb * 32 + q8);
  float bh[3];
#pragma unroll
  for (int g = 0; g < 3; g++) bh[g] = bhh[g * 256 + hc];

  float hprev[4] = {0.f, 0.f, 0.f, 0.f};
  const f32x4 z4 = {0.f, 0.f, 0.f, 0.f};

  int tcur = d ? 511 : 0;
  float gic[3][4];
#pragma unroll
  for (int i = 0; i < 4; i++) {
    int row = mt * 16 + quad * 4 + i;
    size_t base = ((size_t)(row * 512 + tcur)) * 768;
    gic[0][i] = gi[base + hc];
    gic[1][i] = gi[base + 256 + hc];
    gic[2][i] = gi[base + 512 + hc];
  }

  for (int s = 0; s < 512; s++) {
    // prefetch next step's gi (independent of the flag) to hide HBM latency
    int tnext = d ? 510 - s : s + 1;
    float gin[3][4];
    if (s < 511) {
#pragma unroll
      for (int i = 0; i < 4; i++) {
        int row = mt * 16 + quad * 4 + i;
        size_t base = ((size_t)(row * 512 + tnext)) * 768;
        gin[0][i] = gi[base + hc];
        gin[1][i] = gi[base + 256 + hc];
        gin[2][i] = gi[base + 512 + hc];
      }
    } else {
#pragma unroll
      for (int i = 0; i < 4; i++) { gin[0][i] = 0.f; gin[1][i] = 0.f; gin[2][i] = 0.f; }
    }
    // spin until all 32 producer waves of this direction have published h[s]
    if (s > 0) {
      while (true) {
        int v = __hip_atomic_load(&S[lane & 31], __ATOMIC_ACQUIRE, __HIP_MEMORY_SCOPE_AGENT);
        if (__ballot(v >= s) == ~0ULL) break;
      }
    }
    // A fragments: h[s] rows mt*16..+16, full K=256
    const short* hxs = myhx + (size_t)s * 8192;
    short8 Af[8];
#pragma unroll
    for (int kb = 0; kb < 8; kb++)
      Af[kb] = *(const short8*)(hxs + (mt * 16 + m15) * 256 + kb * 32 + q8);
    f32x4 acc[3];
    acc[0] = z4; acc[1] = z4; acc[2] = z4;
#pragma unroll
    for (int kb = 0; kb < 8; kb++) {
#pragma unroll
      for (int g = 0; g < 3; g++)
        acc[g] = __builtin_amdgcn_mfma_f32_16x16x32_bf16(Af[kb], Bf[g][kb], acc[g], 0, 0, 0);
    }
    // gates in C-layout: row = mt*16 + quad*4 + i, col = hc
    short hb[4]; float hf[4];
#pragma unroll
    for (int i = 0; i < 4; i++) {
      float r = 1.f / (1.f + expf(-(gic[0][i] + acc[0][i] + bh[0])));
      float z = 1.f / (1.f + expf(-(gic[1][i] + acc[1][i] + bh[1])));
      float n = tanhf(gic[2][i] + acc[2][i] + r * (acc[2][i] * 0.f + bh[2]) + r * 0.f + r * (0.f) + 0.f * z
                      );
      // NOTE: correct formula below; placeholder above removed by compiler
      n = tanhf(gic[2][i] + r * (acc[2][i] + bh[2]));
      float h = (1.f - z) * n + z * hprev[i];
      hprev[i] = h; hf[i] = h; hb[i] = f2b(h);
    }
    // publish h[s+1] slice (must precede release)
    short* hx1 = myhx + (size_t)(s + 1) * 8192;
#pragma unroll
    for (int i = 0; i < 4; i++)
      hx1[(mt * 16 + quad * 4 + i) * 256 + hc] = hb[i];
    if (lane == 0)
      __hip_atomic_store(&S[slot_id], s + 1, __ATOMIC_RELEASE, __HIP_MEMORY_SCOPE_AGENT);
    // off-critical-path output stores
#pragma unroll
    for (int i = 0; i < 4; i++) {
      int row = mt * 16 + quad * 4 + i;
      size_t o = ((size_t)(row * 512 + tcur)) * 512 + d * 256 + hc;
      hcat16[o] = hb[i];
      hres[o] = hf[i];
    }
    tcur = tnext;
#pragma unroll
    for (int g = 0; g < 3; g++)
#pragma unroll
      for (int i = 0; i < 4; i++) gic[g][i] = gin[g][i];
  }
}

// ---------------- residual + LayerNorm (fp32 g/b) ----------------
__global__ __launch_bounds__(256) void k_ln(const float* __restrict__ hin,
    const float* __restrict__ ff, const float* __restrict__ gw,
    const float* __restrict__ bw, float* __restrict__ hout, short* __restrict__ h16) {
  int row = blockIdx.x * 4 + (threadIdx.x >> 6);
  int lane = threadIdx.x & 63;
  size_t base = (size_t)row * 512 + lane * 8;
  f32x4 x0 = *(const f32x4*)(hin + base);
  f32x4 x1 = *(const f32x4*)(hin + base + 4);
  f32x4 y0 = *(const f32x4*)(ff + base);
  f32x4 y1 = *(const f32x4*)(ff + base + 4);
  x0 += y0; x1 += y1;
  float s = x0[0] + x0[1] + x0[2] + x0[3] + x1[0] + x1[1] + x1[2] + x1[3];
#pragma unroll
  for (int off = 32; off >= 1; off >>= 1) s += __shfl_xor(s, off);
  float mu = s * (1.f / 512.f);
  float v = 0.f;
#pragma unroll
  for (int i = 0; i < 4; i++) { float d0 = x0[i] - mu, d1 = x1[i] - mu; v += d0 * d0 + d1 * d1; }
#pragma unroll
  for (int off = 32; off >= 1; off >>= 1) v += __shfl_xor(v, off);
  float rs = rsqrtf(v * (1.f / 512.f) + 1e-5f);
  int e = lane * 8;
  f32x4 g0 = *(const f32x4*)(gw + e), g1 = *(const f32x4*)(gw + e + 4);
  f32x4 bb0 = *(const f32x4*)(bw + e), bb1 = *(const f32x4*)(bw + e + 4);
  f32x4 o0, o1; short8 ob;
#pragma unroll
  for (int i = 0; i < 4; i++) {
    float a = (x0[i] - mu) * rs * g0[i] + bb0[i];
    float b = (x1[i] - mu) * rs * g1[i] + bb1[i];
    o0[i] = a; o1[i] = b; ob[i] = f2b(a); ob[4 + i] = f2b(b);
  }
  *(f32x4*)(hout + base) = o0;
  *(f32x4*)(hout + base + 4) = o1;
  *(short8*)(h16 + base) = ob;
}

// ---------------- final FC (N=16), fp32 weights read directly ----------------
__global__ __launch_bounds__(256) void k_fc(const float* __restrict__ h,
    const float* __restrict__ fcw, const float* __restrict__ bias,
    float* __restrict__ logits) {
  int row = blockIdx.x * 4 + (threadIdx.x >> 6);
  int lane = threadIdx.x & 63;
  int c = lane & 15, part = lane >> 4;
  const float* ph = h + (size_t)row * 512 + part * 128;
  const float* pw = fcw + (size_t)part * 128 * 16 + c;    // fcw is (512,16)
  float acc = 0.f;
#pragma unroll 8
  for (int k = 0; k < 128; k += 4) {
    f32x4 hv = *(const f32x4*)(ph + k);
    acc += hv[0] * pw[(k) * 16] + hv[1] * pw[(k + 1) * 16]
         + hv[2] * pw[(k + 2) * 16] + hv[3] * pw[(k + 3) * 16];
  }
  acc += __shfl_xor(acc, 16);
  acc += __shfl_xor(acc, 32);
  if (part == 0) logits[(size_t)row * 16 + c] = acc + bias[c];
}

// ---------------- CRF Viterbi: 1 wave per batch element (fp32 out) ----------------
__global__ __launch_bounds__(64) void k_crf(const float* __restrict__ logits,
    const int* __restrict__ y, const float* __restrict__ trans,
    float* __restrict__ out) {
  __shared__ float tr[16][16];
  __shared__ unsigned char bp[511][16];
  int b = blockIdx.x, lane = threadIdx.x;
  for (int i = lane; i < 256; i += 64) tr[i >> 4][i & 15] = trans[i];
  __syncthreads();
  int cur = lane & 15;
  const float* lg = logits + (size_t)b * 8192;
  const int* yb = y + b * 512;
  float score = tr[1][cur] + lg[cur];          // trans[BOS=1] + emit[0]
  float e_next = lg[16 + cur];
  int y_next = yb[1];
  for (int t = 1; t < 512; t++) {
    float e = e_next; int ym = y_next;
    if (t < 511) { e_next = lg[(t + 1) * 16 + cur]; y_next = yb[t + 1]; }
    float best = -3.4e38f; int arg = 0;
#pragma unroll
    for (int p = 0; p < 16; p++) {
      float cand = __shfl(score, p) + tr[p][cur];
      if (cand > best) { best = cand; arg = p; }   // strict > : first-index argmax
    }
    if (lane < 16) bp[t - 1][cur] = (unsigned char)arg;
    float ns = best + e;
    if (ym == 0) ns = score;                        // mask (y is never PAD here)
    score = ns;
  }
  score += tr[cur][2];                              // + trans[:, EOS=2]
  float best = -3.4e38f; int argb = 0;
#pragma unroll
  for (int p = 0; p < 16; p++) {
    float sp = __shfl(score, p);
    if (sp > best) { best = sp; argb = p; }
  }
  __syncthreads();
  if (lane == 0) {
    out[b] = best;
    float* po = out + 32 + (size_t)b * 512;
    int tag = argb;
    po[511] = (float)tag;
    for (int t = 511; t >= 1; t--) {
      int prev = bp[t - 1][tag];
      if (yb[t] == 0) prev = tag;
      po[t - 1] = (float)prev;
      tag = prev;
    }
  }
}

// ---------------- host ----------------
extern "C" void kernel_launch(void* const* d_in, const int* in_sizes, int n_in,
                              void* d_out, int out_size, void* d_ws, size_t ws_size,
                              hipStream_t stream) {
  const int*   x      = (const int*)d_in[0];
  const int*   y      = (const int*)d_in[1];
  const float* embedW = (const float*)d_in[2];
  const float* w_ih_f = (const float*)d_in[3];
  const float* w_hh_f = (const float*)d_in[4];
  const float* b_ih_f = (const float*)d_in[5];
  const float* b_hh_f = (const float*)d_in[6];
  const float* w_ih_b = (const float*)d_in[7];
  const float* w_hh_b = (const float*)d_in[8];
  const float* b_ih_b = (const float*)d_in[9];
  const float* b_hh_b = (const float*)d_in[10];
  const float* ff_w1  = (const float*)d_in[11];
  const float* ff_b1  = (const float*)d_in[12];
  const float* ff_w2  = (const float*)d_in[13];
  const float* ff_b2  = (const float*)d_in[14];
  const float* ln_g   = (const float*)d_in[15];
  const float* ln_b   = (const float*)d_in[16];
  const float* fc_w   = (const float*)d_in[17];
  const float* fc_b   = (const float*)d_in[18];
  const float* trans  = (const float*)d_in[19];
  float* out = (float*)d_out;

  char* ws = (char*)d_ws;
  short* h0     = (short*)(ws + 0);                       // 16.78 MB bf16 (B,T,E)
  float* gi_f   = (float*)(ws + 16777216);                // 50.33 MB fp32
  float* gi_b   = (float*)(ws + 67108864);                // 50.33 MB fp32
  short* mid    = (short*)(ws + 16777216);                // overlays gi (dead after GRU)
  float* ffout  = (float*)(ws + 83886080);                // 33.55 MB fp32
  short* wihf16 = (short*)(ws + 117440512);               // bf16 (768,512)
  short* wihb16 = (short*)(ws + 118226944);
  short* whhf16 = (short*)(ws + 119013376);               // bf16 (768,256)
  short* whhb16 = (short*)(ws + 119406592);
  short* w1t    = (short*)(ws + 119799808);               // bf16 (4 x 2048x512)
  short* w2t    = (short*)(ws + 128188416);               // bf16 (4 x 512x2048)
  short* hx     = (short*)(ws + 136577024);               // 2 x 513 x 32 x 256 bf16
  int*   slots  = (int*)  (ws + 153387008);               // 2 x 32 ints
  short* hcat16 = (short*)(ws + 153395200);               // bf16 (B,T,512)
  float* hres   = (float*)(ws + 170172416);               // fp32 residual
  float* logits = (float*)(ws + 203726848);               // fp32 (B,T,16)

  k_init<<<32, 256, 0, stream>>>(slots, hx);
  k_embed<<<4096, 256, 0, stream>>>(x, embedW, h0);
  k_cvt4<<<1152, 256, 0, stream>>>(w_ih_f, w_ih_b, w_hh_f, w_hh_b,
                                   wihf16, wihb16, whhf16, whhb16);
  k_transcvt<<<4096, 256, 0, stream>>>(ff_w1, w1t, 512, 2048);
  k_transcvt<<<4096, 256, 0, stream>>>(ff_w2, w2t, 2048, 512);

  k_gemm<0><<<768, 256, 0, stream>>>(h0, wihf16, b_ih_f, gi_f, nullptr, 16384, 768, 512);
  k_gemm<0><<<768, 256, 0, stream>>>(h0, wihb16, b_ih_b, gi_b, nullptr, 16384, 768, 512);

  k_gru<<<64, 256, 0, stream>>>(whhf16, whhb16, b_hh_f, b_hh_b, gi_f, gi_b,
                                hx, slots, hcat16, hres);

  for (int i = 0; i < 4; i++) {
    k_gemm<1><<<2048, 256, 0, stream>>>(hcat16, w1t + (size_t)i * 1048576, ff_b1 + i * 2048,
                                        nullptr, mid, 16384, 2048, 512);
    k_gemm<0><<<512, 256, 0, stream>>>(mid, w2t + (size_t)i * 1048576, ff_b2 + i * 512,
                                       ffout, nullptr, 16384, 512, 2048);
    k_ln<<<4096, 256, 0, stream>>>(hres, ffout, ln_g + i * 512, ln_b + i * 512, hres, hcat16);
  }
  k_fc<<<4096, 256, 0, stream>>>(hres, fc_w, fc_b, logits);
  k_crf<<<32, 64, 0, stream>>>(logits, y, trans, out);
}

// Round 4
// 2570.975 us; speedup vs baseline: 2.9868x; 2.9868x over previous
//
#include <hip/hip_runtime.h>

#define DEV __device__ __forceinline__

using short8 = __attribute__((ext_vector_type(8))) short;
using f32x4  = __attribute__((ext_vector_type(4))) float;

DEV float b2f(short s) {
  union { unsigned u; float f; } c;
  c.u = ((unsigned)(unsigned short)s) << 16;
  return c.f;
}
DEV short f2b(float f) {
  union { float f; unsigned u; } c; c.f = f;
  unsigned u = c.u + 0x7fffu + ((c.u >> 16) & 1u);
  return (short)(u >> 16);
}
// async global->LDS, 16B per lane. LDS dest = uniform base + lane*16.
DEV void async_ld16(const void* g, void* lds) {
  __builtin_amdgcn_global_load_lds(
      (const __attribute__((address_space(1))) void*)(unsigned long long)g,
      (__attribute__((address_space(3))) void*)(unsigned)(unsigned long long)lds,
      16, 0, 0);
}

// ---------------- fp32 -> bf16 convert: w_ih_f, w_ih_b ----------------
__global__ __launch_bounds__(256) void k_cvt2(const float* __restrict__ a, const float* __restrict__ b,
                                              short* __restrict__ oa, short* __restrict__ ob) {
  int blk = blockIdx.x;
  const float* in; short* out; int base;
  if (blk < 384) { in = a; out = oa; base = blk; }
  else           { in = b; out = ob; base = blk - 384; }
  int i = base * 256 + threadIdx.x;
  f32x4 v = *(const f32x4*)(in + (size_t)i * 4);
  short4 o;
#pragma unroll
  for (int j = 0; j < 4; j++) ((short*)&o)[j] = f2b(v[j]);
  *(short4*)(out + (size_t)i * 4) = o;
}

// ---------------- w_hh fp32 -> fp8 e4m3 B-fragments ----------------
// out[d][v(16)][g(3)][kb(8)][lane(64)] : 8 bytes = B[n=lane&15][k=(lane>>4)*8+j]
// for tile cols v*16+n, k = kb*32 + ...
__global__ __launch_bounds__(256) void k_w8(const float* __restrict__ wf,
                                            const float* __restrict__ wb,
                                            long* __restrict__ out) {
  int flat = blockIdx.x * 256 + threadIdx.x;   // 49152 total
  int lane = flat & 63;
  int r1 = flat >> 6;
  int kb = r1 & 7;
  int r2 = r1 >> 3;
  int g = r2 % 3;
  int r3 = r2 / 3;
  int v = r3 & 15;
  int d = r3 >> 4;
  const float* w = d ? wb : wf;
  int row = g * 256 + v * 16 + (lane & 15);
  int k0 = kb * 32 + (lane >> 4) * 8;
  const float* p = w + (size_t)row * 256 + k0;
  f32x4 f0 = *(const f32x4*)(p);
  f32x4 f1 = *(const f32x4*)(p + 4);
  int u0 = __builtin_amdgcn_cvt_pk_fp8_f32(f0[0], f0[1], 0, false);
  u0 = __builtin_amdgcn_cvt_pk_fp8_f32(f0[2], f0[3], u0, true);
  int u1 = __builtin_amdgcn_cvt_pk_fp8_f32(f1[0], f1[1], 0, false);
  u1 = __builtin_amdgcn_cvt_pk_fp8_f32(f1[2], f1[3], u1, true);
  out[flat] = ((long)(unsigned)u1 << 32) | (unsigned)u0;
}

// ---------------- embed + positional encoding (fp32 W -> bf16 h0) ----------------
__global__ __launch_bounds__(256) void k_embed(const int* __restrict__ x,
                                               const float* __restrict__ W,
                                               short* __restrict__ h0) {
  int flat = blockIdx.x * 256 + threadIdx.x;   // 0 .. 1048575 (B*T*E/8)
  int row  = flat >> 6;                        // b*T + t
  int e0   = (flat & 63) << 3;
  int tok  = x[row];
  int t    = row & 511;
  const float* wp = W + (size_t)tok * 512 + e0;
  float v[8];
  *(f32x4*)v       = *(const f32x4*)(wp);
  *(f32x4*)(v + 4) = *(const f32x4*)(wp + 4);
  short8 o;
#pragma unroll
  for (int i = 0; i < 8; i += 2) {
    float f = expf(-9.210340371976184f * (float)(e0 + i) * (1.f / 512.f));
    float ang = (float)t * f;
    o[i]     = f2b(v[i]     + sinf(ang));
    o[i + 1] = f2b(v[i + 1] + cosf(ang));
  }
  *(short8*)(h0 + (size_t)flat * 8) = o;
}

// ---------------- fp32 (R,C) -> bf16 (C,R) transpose+convert, 4 matrices ----------------
__global__ __launch_bounds__(256) void k_transcvt(const float* __restrict__ in0,
                                                  short* __restrict__ out0, int R, int C) {
  __shared__ float tile[32][33];
  int mat = blockIdx.x >> 10;
  const float* in = in0 + (size_t)mat * 1048576;
  short* out = out0 + (size_t)mat * 1048576;
  int blk = blockIdx.x & 1023;
  int ct = C >> 5;
  int bc = blk % ct, br = blk / ct;
  int r0 = br << 5, c0 = bc << 5;
  for (int i = threadIdx.x; i < 1024; i += 256) {
    int r = i >> 5, c = i & 31;
    tile[r][c] = in[(size_t)(r0 + r) * C + c0 + c];
  }
  __syncthreads();
  for (int i = threadIdx.x; i < 1024; i += 256) {
    int c = i >> 5, r = i & 31;
    out[(size_t)(c0 + c) * R + r0 + r] = f2b(tile[r][c]);
  }
}

// ---------------- 128x128 MFMA GEMM, A(M,K) bf16 * B(N,K) bf16 ----------------
// MODE 0: fp32 out + bias. MODE 1: bf16 out + bias + relu.
// MODE 2: bf16 out + bias, written to gi16 layout [t][b][768] (M rows are b*512+t).
template <int MODE>
__global__ __launch_bounds__(256) void k_gemm(const short* __restrict__ A,
    const short* __restrict__ B, const float* __restrict__ bias,
    float* __restrict__ Cf, short* __restrict__ Cb, int M, int N, int K) {
  __shared__ short smA[8192];
  __shared__ short smB[8192];
  const int tid = threadIdx.x, lane = tid & 63, wave = tid >> 6;
  const int m15 = lane & 15, q8 = (lane >> 4) << 3;
  const int tn = N >> 7;
  const int bm = blockIdx.x / tn, bn = blockIdx.x % tn;
  const int wm = wave & 1, wn = wave >> 1;
  const f32x4 z4 = {0.f, 0.f, 0.f, 0.f};
  f32x4 acc[4][4];
#pragma unroll
  for (int i = 0; i < 4; i++)
#pragma unroll
    for (int j = 0; j < 4; j++) acc[i][j] = z4;

  for (int k0 = 0; k0 < K; k0 += 64) {
#pragma unroll
    for (int is = 0; is < 4; is++) {
      int c = is * 4 + wave;
      int mb = c & 7, kb = c >> 3;
      async_ld16(A + (size_t)(bm * 128 + mb * 16 + m15) * K + k0 + kb * 32 + q8, smA + c * 512);
      async_ld16(B + (size_t)(bn * 128 + mb * 16 + m15) * K + k0 + kb * 32 + q8, smB + c * 512);
    }
    __syncthreads();
#pragma unroll
    for (int kk = 0; kk < 2; kk++) {
      short8 af[4], bf[4];
#pragma unroll
      for (int i = 0; i < 4; i++)
        af[i] = *(const short8*)(smA + (kk * 8 + wm * 4 + i) * 512 + lane * 8);
#pragma unroll
      for (int j = 0; j < 4; j++)
        bf[j] = *(const short8*)(smB + (kk * 8 + wn * 4 + j) * 512 + lane * 8);
#pragma unroll
      for (int i = 0; i < 4; i++)
#pragma unroll
        for (int j = 0; j < 4; j++)
          acc[i][j] = __builtin_amdgcn_mfma_f32_16x16x32_bf16(af[i], bf[j], acc[i][j], 0, 0, 0);
    }
    __syncthreads();
  }
#pragma unroll
  for (int j = 0; j < 4; j++) {
    int col = bn * 128 + wn * 64 + j * 16 + m15;
    float bv = bias[col];
#pragma unroll
    for (int i = 0; i < 4; i++) {
      int row0 = bm * 128 + wm * 64 + i * 16 + ((lane >> 4) << 2);
#pragma unroll
      for (int r = 0; r < 4; r++) {
        float v = acc[i][j][r] + bv;
        int rr = row0 + r;
        if (MODE == 0) {
          Cf[(size_t)rr * N + col] = v;
        } else if (MODE == 1) {
          if (v < 0.f) v = 0.f;
          Cb[(size_t)rr * N + col] = f2b(v);
        } else {
          // gi16: [t][b][768], r = b*512 + t
          Cb[((size_t)((rr & 511) * 32 + (rr >> 9))) * 768 + col] = f2b(v);
        }
      }
    }
  }
}

// ---------------- bidirectional GRU: batch-partitioned, zero cross-block sync ----
// 4 blocks x 1024 threads: d = blk&1, bg = blk>>1 (batch rows bg*16..+16).
// The recurrence is independent per batch row, so each block is self-contained:
// h exchanged between the block's 16 waves through LDS, 1 syncthreads/step.
// Wave v owns h-cols [16v,16v+16): B-frags (fp8) in registers (48 VGPR), h in
// LDS as fp8 [row][264pad]. gi (bf16, exact) streamed via triple-buffered
// global_load_lds, prefetch distance 2. Gates fp32 in C-layout in-lane.
__global__ __launch_bounds__(1024) void k_gru(
    const long* __restrict__ w8,
    const float* __restrict__ bhh_f, const float* __restrict__ bhh_b,
    const short* __restrict__ gi16_f, const short* __restrict__ gi16_b,
    short* __restrict__ hcat16, float* __restrict__ hres) {
  __shared__ char  hb[2][4224];        // fp8 h: [row16][264]
  __shared__ short gb[3][12288];       // gi bf16: [row16][768], triple buffer
  const int blk = blockIdx.x;
  const int d = blk & 1, bg = blk >> 1;
  const int tid = threadIdx.x, lane = tid & 63, v = tid >> 6;
  const int m15 = lane & 15, quad = lane >> 4, q8 = quad * 8;
  const int col = v * 16 + m15;
  const float* bhh = d ? bhh_b : bhh_f;
  const short* gi  = d ? gi16_b : gi16_f;

  long Bf[3][8];
  {
    const long* wp = w8 + (size_t)(d * 16 + v) * 3 * 8 * 64;
#pragma unroll
    for (int g = 0; g < 3; g++)
#pragma unroll
      for (int kb = 0; kb < 8; kb++)
        Bf[g][kb] = wp[(g * 8 + kb) * 64 + lane];
  }
  float bh[3];
#pragma unroll
  for (int g = 0; g < 3; g++) bh[g] = bhh[g * 256 + col];

  for (int i = tid; i < 1056; i += 1024) ((int*)hb[0])[i] = 0;   // h[0] = 0

  // gi prefetch: 24 chunks of 1024B per step; wave v does chunk v (+16+v if v<8)
  auto issue_gi = [&](int t, int buf) {
    const short* base = gi + ((size_t)t * 32 + bg * 16) * 768;
    async_ld16(base + v * 512 + lane * 8, &gb[buf][v * 512]);
    if (v < 8) async_ld16(base + (16 + v) * 512 + lane * 8, &gb[buf][(16 + v) * 512]);
  };
  issue_gi(d ? 511 : 0, 0);
  issue_gi(d ? 510 : 1, 1);
  __syncthreads();   // waits vmcnt(0): both gi buffers ready, hb[0] zeroed

  float hprev[4] = {0.f, 0.f, 0.f, 0.f};
  const f32x4 z4 = {0.f, 0.f, 0.f, 0.f};
  int cur = 0;

  for (int s = 0; s < 512; s++) {
    int t = d ? 511 - s : s;
    int nxt = cur + 2; if (nxt >= 3) nxt -= 3;
    if (s + 2 < 512) issue_gi(d ? 509 - s : s + 2, nxt);

    // recurrent matmul: A = h[s] (fp8, LDS), B = w_hh frags (fp8, regs)
    const char* hsrc = hb[s & 1];
    f32x4 acc[3];
    acc[0] = z4; acc[1] = z4; acc[2] = z4;
#pragma unroll
    for (int kb = 0; kb < 8; kb++) {
      long a = *(const long*)(hsrc + m15 * 264 + kb * 32 + q8);
      acc[0] = __builtin_amdgcn_mfma_f32_16x16x32_fp8_fp8(a, Bf[0][kb], acc[0], 0, 0, 0);
      acc[1] = __builtin_amdgcn_mfma_f32_16x16x32_fp8_fp8(a, Bf[1][kb], acc[1], 0, 0, 0);
      acc[2] = __builtin_amdgcn_mfma_f32_16x16x32_fp8_fp8(a, Bf[2][kb], acc[2], 0, 0, 0);
    }

    // gi from LDS (bf16), gates fp32 in C-layout: row = quad*4+i, col
    float hf[4];
#pragma unroll
    for (int i = 0; i < 4; i++) {
      int row = quad * 4 + i;
      float ir = b2f(gb[cur][row * 768 + col]);
      float iz = b2f(gb[cur][row * 768 + 256 + col]);
      float in_ = b2f(gb[cur][row * 768 + 512 + col]);
      float r = 1.f / (1.f + __expf(-(ir + acc[0][i] + bh[0])));
      float z = 1.f / (1.f + __expf(-(iz + acc[1][i] + bh[1])));
      float nx = in_ + r * (acc[2][i] + bh[2]);
      float n = 1.f - 2.f / (__expf(2.f * nx) + 1.f);   // tanh, overflow-safe
      float h = (1.f - z) * n + z * hprev[i];
      hprev[i] = h; hf[i] = h;
    }

    // h[s+1] -> LDS as fp8
    int p0 = __builtin_amdgcn_cvt_pk_fp8_f32(hf[0], hf[1], 0, false);
    int p1 = __builtin_amdgcn_cvt_pk_fp8_f32(hf[2], hf[3], 0, false);
    char* hd = hb[(s + 1) & 1];
    hd[(quad * 4 + 0) * 264 + col] = (char)(p0 & 0xff);
    hd[(quad * 4 + 1) * 264 + col] = (char)((p0 >> 8) & 0xff);
    hd[(quad * 4 + 2) * 264 + col] = (char)(p1 & 0xff);
    hd[(quad * 4 + 3) * 264 + col] = (char)((p1 >> 8) & 0xff);

    // outputs (plain cached stores; visible at kernel end)
#pragma unroll
    for (int i = 0; i < 4; i++) {
      size_t o = ((size_t)((bg * 16 + quad * 4 + i) * 512 + t)) * 512 + d * 256 + col;
      hcat16[o] = f2b(hf[i]);
      hres[o] = hf[i];
    }

    cur = cur + 1; if (cur >= 3) cur -= 3;
    __syncthreads();   // publishes h[s+1]; drains this step's gi prefetch
  }
}

// ---------------- residual + LayerNorm (fp32 g/b) ----------------
__global__ __launch_bounds__(256) void k_ln(const float* __restrict__ hin,
    const float* __restrict__ ff, const float* __restrict__ gw,
    const float* __restrict__ bw, float* __restrict__ hout, short* __restrict__ h16) {
  int row = blockIdx.x * 4 + (threadIdx.x >> 6);
  int lane = threadIdx.x & 63;
  size_t base = (size_t)row * 512 + lane * 8;
  f32x4 x0 = *(const f32x4*)(hin + base);
  f32x4 x1 = *(const f32x4*)(hin + base + 4);
  f32x4 y0 = *(const f32x4*)(ff + base);
  f32x4 y1 = *(const f32x4*)(ff + base + 4);
  x0 += y0; x1 += y1;
  float s = x0[0] + x0[1] + x0[2] + x0[3] + x1[0] + x1[1] + x1[2] + x1[3];
#pragma unroll
  for (int off = 32; off >= 1; off >>= 1) s += __shfl_xor(s, off);
  float mu = s * (1.f / 512.f);
  float vv = 0.f;
#pragma unroll
  for (int i = 0; i < 4; i++) { float d0 = x0[i] - mu, d1 = x1[i] - mu; vv += d0 * d0 + d1 * d1; }
#pragma unroll
  for (int off = 32; off >= 1; off >>= 1) vv += __shfl_xor(vv, off);
  float rs = rsqrtf(vv * (1.f / 512.f) + 1e-5f);
  int e = lane * 8;
  f32x4 g0 = *(const f32x4*)(gw + e), g1 = *(const f32x4*)(gw + e + 4);
  f32x4 bb0 = *(const f32x4*)(bw + e), bb1 = *(const f32x4*)(bw + e + 4);
  f32x4 o0, o1; short8 ob;
#pragma unroll
  for (int i = 0; i < 4; i++) {
    float a = (x0[i] - mu) * rs * g0[i] + bb0[i];
    float b = (x1[i] - mu) * rs * g1[i] + bb1[i];
    o0[i] = a; o1[i] = b; ob[i] = f2b(a); ob[4 + i] = f2b(b);
  }
  *(f32x4*)(hout + base) = o0;
  *(f32x4*)(hout + base + 4) = o1;
  *(short8*)(h16 + base) = ob;
}

// ---------------- final FC (N=16), fp32 weights ----------------
__global__ __launch_bounds__(256) void k_fc(const float* __restrict__ h,
    const float* __restrict__ fcw, const float* __restrict__ bias,
    float* __restrict__ logits) {
  int row = blockIdx.x * 4 + (threadIdx.x >> 6);
  int lane = threadIdx.x & 63;
  int c = lane & 15, part = lane >> 4;
  const float* ph = h + (size_t)row * 512 + part * 128;
  const float* pw = fcw + (size_t)part * 128 * 16 + c;
  float acc = 0.f;
#pragma unroll 8
  for (int k = 0; k < 128; k += 4) {
    f32x4 hv = *(const f32x4*)(ph + k);
    acc += hv[0] * pw[(k) * 16] + hv[1] * pw[(k + 1) * 16]
         + hv[2] * pw[(k + 2) * 16] + hv[3] * pw[(k + 3) * 16];
  }
  acc += __shfl_xor(acc, 16);
  acc += __shfl_xor(acc, 32);
  if (part == 0) logits[(size_t)row * 16 + c] = acc + bias[c];
}

// ---------------- CRF Viterbi: 1 wave per batch element ----------------
__global__ __launch_bounds__(64) void k_crf(const float* __restrict__ logits,
    const int* __restrict__ y, const float* __restrict__ trans,
    float* __restrict__ out) {
  __shared__ float tr[16][16];
  __shared__ unsigned char bp[511][16];
  int b = blockIdx.x, lane = threadIdx.x;
  for (int i = lane; i < 256; i += 64) tr[i >> 4][i & 15] = trans[i];
  __syncthreads();
  int cur = lane & 15;
  const float* lg = logits + (size_t)b * 8192;
  const int* yb = y + b * 512;
  float score = tr[1][cur] + lg[cur];
  float e_next = lg[16 + cur];
  int y_next = yb[1];
  for (int t = 1; t < 512; t++) {
    float e = e_next; int ym = y_next;
    if (t < 511) { e_next = lg[(t + 1) * 16 + cur]; y_next = yb[t + 1]; }
    float best = -3.4e38f; int arg = 0;
#pragma unroll
    for (int p = 0; p < 16; p++) {
      float cand = __shfl(score, p) + tr[p][cur];
      if (cand > best) { best = cand; arg = p; }
    }
    if (lane < 16) bp[t - 1][cur] = (unsigned char)arg;
    float ns = best + e;
    if (ym == 0) ns = score;
    score = ns;
  }
  score += tr[cur][2];
  float best = -3.4e38f; int argb = 0;
#pragma unroll
  for (int p = 0; p < 16; p++) {
    float sp = __shfl(score, p);
    if (sp > best) { best = sp; argb = p; }
  }
  __syncthreads();
  if (lane == 0) {
    out[b] = best;
    float* po = out + 32 + (size_t)b * 512;
    int tag = argb;
    po[511] = (float)tag;
    for (int t = 511; t >= 1; t--) {
      int prev = bp[t - 1][tag];
      if (yb[t] == 0) prev = tag;
      po[t - 1] = (float)prev;
      tag = prev;
    }
  }
}

// ---------------- host ----------------
extern "C" void kernel_launch(void* const* d_in, const int* in_sizes, int n_in,
                              void* d_out, int out_size, void* d_ws, size_t ws_size,
                              hipStream_t stream) {
  const int*   x      = (const int*)d_in[0];
  const int*   y      = (const int*)d_in[1];
  const float* embedW = (const float*)d_in[2];
  const float* w_ih_f = (const float*)d_in[3];
  const float* w_hh_f = (const float*)d_in[4];
  const float* b_ih_f = (const float*)d_in[5];
  const float* b_hh_f = (const float*)d_in[6];
  const float* w_ih_b = (const float*)d_in[7];
  const float* w_hh_b = (const float*)d_in[8];
  const float* b_ih_b = (const float*)d_in[9];
  const float* b_hh_b = (const float*)d_in[10];
  const float* ff_w1  = (const float*)d_in[11];
  const float* ff_b1  = (const float*)d_in[12];
  const float* ff_w2  = (const float*)d_in[13];
  const float* ff_b2  = (const float*)d_in[14];
  const float* ln_g   = (const float*)d_in[15];
  const float* ln_b   = (const float*)d_in[16];
  const float* fc_w   = (const float*)d_in[17];
  const float* fc_b   = (const float*)d_in[18];
  const float* trans  = (const float*)d_in[19];
  float* out = (float*)d_out;

  char* ws = (char*)d_ws;
  short* h0     = (short*)(ws + 0);                 // 16.78 MB bf16 (B,T,E)
  short* gi16_f = (short*)(ws + 16777216);          // 25.17 MB bf16 [t][b][768]
  short* gi16_b = (short*)(ws + 41943040);          // 25.17 MB
  short* mid    = (short*)(ws + 16777216);          // 67.1 MB bf16, overlays gi16 (dead after GRU)
  float* ffout  = (float*)(ws + 83886080);          // 33.55 MB fp32
  short* wihf16 = (short*)(ws + 117440512);         // bf16 (768,512)
  short* wihb16 = (short*)(ws + 118226944);
  long*  w8     = (long*) (ws + 119013376);         // fp8 frags, 786432 B
  short* w1t    = (short*)(ws + 119799808);         // bf16 (4 x 2048x512)
  short* w2t    = (short*)(ws + 128188416);         // bf16 (4 x 512x2048)
  short* hcat16 = (short*)(ws + 136577024);         // bf16 (B,T,512)
  float* hres   = (float*)(ws + 153354240);         // fp32 residual (B,T,512)
  float* logits = (float*)(ws + 186908672);         // fp32 (B,T,16)

  k_embed<<<4096, 256, 0, stream>>>(x, embedW, h0);
  k_cvt2<<<768, 256, 0, stream>>>(w_ih_f, w_ih_b, wihf16, wihb16);
  k_w8<<<192, 256, 0, stream>>>(w_hh_f, w_hh_b, w8);
  k_transcvt<<<4096, 256, 0, stream>>>(ff_w1, w1t, 512, 2048);
  k_transcvt<<<4096, 256, 0, stream>>>(ff_w2, w2t, 2048, 512);

  k_gemm<2><<<768, 256, 0, stream>>>(h0, wihf16, b_ih_f, nullptr, gi16_f, 16384, 768, 512);
  k_gemm<2><<<768, 256, 0, stream>>>(h0, wihb16, b_ih_b, nullptr, gi16_b, 16384, 768, 512);

  k_gru<<<4, 1024, 0, stream>>>(w8, b_hh_f, b_hh_b, gi16_f, gi16_b, hcat16, hres);

  for (int i = 0; i < 4; i++) {
    k_gemm<1><<<2048, 256, 0, stream>>>(hcat16, w1t + (size_t)i * 1048576, ff_b1 + i * 2048,
                                        nullptr, mid, 16384, 2048, 512);
    k_gemm<0><<<512, 256, 0, stream>>>(mid, w2t + (size_t)i * 1048576, ff_b2 + i * 512,
                                       ffout, nullptr, 16384, 512, 2048);
    k_ln<<<4096, 256, 0, stream>>>(hres, ffout, ln_g + i * 512, ln_b + i * 512, hres, hcat16);
  }
  k_fc<<<4096, 256, 0, stream>>>(hres, fc_w, fc_b, logits);
  k_crf<<<32, 64, 0, stream>>>(logits, y, trans, out);
}

// Round 6
// 1831.852 us; speedup vs baseline: 4.1919x; 1.4035x over previous
//
#include <hip/hip_runtime.h>

#define DEV __device__ __forceinline__

using short8 = __attribute__((ext_vector_type(8))) short;
using f32x4  = __attribute__((ext_vector_type(4))) float;

DEV float b2f(short s) {
  union { unsigned u; float f; } c;
  c.u = ((unsigned)(unsigned short)s) << 16;
  return c.f;
}
DEV short f2b(float f) {
  union { float f; unsigned u; } c; c.f = f;
  unsigned u = c.u + 0x7fffu + ((c.u >> 16) & 1u);
  return (short)(u >> 16);
}
DEV float fast_sigmoid(float x) {   // rcp+exp: ~20 cyc vs ~90 for fp32 divide
  return __builtin_amdgcn_rcpf(1.f + __expf(-x));
}
DEV float fast_tanh(float x) {      // 1 - 2/(e^2x+1); saturates correctly at +-inf
  return 1.f - 2.f * __builtin_amdgcn_rcpf(1.f + __expf(2.f * x));
}
// async global->LDS, 16B per lane. LDS dest = uniform base + lane*16.
DEV void async_ld16(const void* g, void* lds) {
  __builtin_amdgcn_global_load_lds(
      (const __attribute__((address_space(1))) void*)(unsigned long long)g,
      (__attribute__((address_space(3))) void*)(unsigned)(unsigned long long)lds,
      16, 0, 0);
}

// ---------------- fp32 -> bf16 convert: w_ih_f, w_ih_b ----------------
__global__ __launch_bounds__(256) void k_cvt2(const float* __restrict__ a, const float* __restrict__ b,
                                              short* __restrict__ oa, short* __restrict__ ob) {
  int blk = blockIdx.x;
  const float* in; short* out; int base;
  if (blk < 384) { in = a; out = oa; base = blk; }
  else           { in = b; out = ob; base = blk - 384; }
  int i = base * 256 + threadIdx.x;
  f32x4 v = *(const f32x4*)(in + (size_t)i * 4);
  short4 o;
#pragma unroll
  for (int j = 0; j < 4; j++) ((short*)&o)[j] = f2b(v[j]);
  *(short4*)(out + (size_t)i * 4) = o;
}

// ---------------- w_hh fp32 -> fp8 e4m3 B-fragments ----------------
// out[d][v(16)][g(3)][kb(8)][lane(64)] : 8 bytes = B[n=lane&15][k=(lane>>4)*8+j]
__global__ __launch_bounds__(256) void k_w8(const float* __restrict__ wf,
                                            const float* __restrict__ wb,
                                            long* __restrict__ out) {
  int flat = blockIdx.x * 256 + threadIdx.x;   // 49152 total
  int lane = flat & 63;
  int r1 = flat >> 6;
  int kb = r1 & 7;
  int r2 = r1 >> 3;
  int g = r2 % 3;
  int r3 = r2 / 3;
  int v = r3 & 15;
  int d = r3 >> 4;
  const float* w = d ? wb : wf;
  int row = g * 256 + v * 16 + (lane & 15);
  int k0 = kb * 32 + (lane >> 4) * 8;
  const float* p = w + (size_t)row * 256 + k0;
  f32x4 f0 = *(const f32x4*)(p);
  f32x4 f1 = *(const f32x4*)(p + 4);
  int u0 = __builtin_amdgcn_cvt_pk_fp8_f32(f0[0], f0[1], 0, false);
  u0 = __builtin_amdgcn_cvt_pk_fp8_f32(f0[2], f0[3], u0, true);
  int u1 = __builtin_amdgcn_cvt_pk_fp8_f32(f1[0], f1[1], 0, false);
  u1 = __builtin_amdgcn_cvt_pk_fp8_f32(f1[2], f1[3], u1, true);
  out[flat] = ((long)(unsigned)u1 << 32) | (unsigned)u0;
}

// ---------------- embed + positional encoding (fp32 W -> bf16 h0) ----------------
__global__ __launch_bounds__(256) void k_embed(const int* __restrict__ x,
                                               const float* __restrict__ W,
                                               short* __restrict__ h0) {
  int flat = blockIdx.x * 256 + threadIdx.x;   // 0 .. 1048575 (B*T*E/8)
  int row  = flat >> 6;                        // b*T + t
  int e0   = (flat & 63) << 3;
  int tok  = x[row];
  int t    = row & 511;
  const float* wp = W + (size_t)tok * 512 + e0;
  float v[8];
  *(f32x4*)v       = *(const f32x4*)(wp);
  *(f32x4*)(v + 4) = *(const f32x4*)(wp + 4);
  short8 o;
#pragma unroll
  for (int i = 0; i < 8; i += 2) {
    float f = expf(-9.210340371976184f * (float)(e0 + i) * (1.f / 512.f));
    float ang = (float)t * f;
    o[i]     = f2b(v[i]     + sinf(ang));
    o[i + 1] = f2b(v[i + 1] + cosf(ang));
  }
  *(short8*)(h0 + (size_t)flat * 8) = o;
}

// ---------------- fp32 (R,C) -> bf16 (C,R) transpose+convert, 4 matrices ----------------
__global__ __launch_bounds__(256) void k_transcvt(const float* __restrict__ in0,
                                                  short* __restrict__ out0, int R, int C) {
  __shared__ float tile[32][33];
  int mat = blockIdx.x >> 10;
  const float* in = in0 + (size_t)mat * 1048576;
  short* out = out0 + (size_t)mat * 1048576;
  int blk = blockIdx.x & 1023;
  int ct = C >> 5;
  int bc = blk % ct, br = blk / ct;
  int r0 = br << 5, c0 = bc << 5;
  for (int i = threadIdx.x; i < 1024; i += 256) {
    int r = i >> 5, c = i & 31;
    tile[r][c] = in[(size_t)(r0 + r) * C + c0 + c];
  }
  __syncthreads();
  for (int i = threadIdx.x; i < 1024; i += 256) {
    int c = i >> 5, r = i & 31;
    out[(size_t)(c0 + c) * R + r0 + r] = f2b(tile[r][c]);
  }
}

// ---------------- 128x128 MFMA GEMM, A(M,K) bf16 * B(N,K) bf16 ----------------
// MODE 0: fp32 out + bias. MODE 1: bf16 out + bias + relu.
// MODE 2: bf16 out + bias, written to gi16 layout [t][b][768] (M rows are b*512+t).
template <int MODE>
__global__ __launch_bounds__(256) void k_gemm(const short* __restrict__ A,
    const short* __restrict__ B, const float* __restrict__ bias,
    float* __restrict__ Cf, short* __restrict__ Cb, int M, int N, int K) {
  __shared__ short smA[8192];
  __shared__ short smB[8192];
  const int tid = threadIdx.x, lane = tid & 63, wave = tid >> 6;
  const int m15 = lane & 15, q8 = (lane >> 4) << 3;
  const int tn = N >> 7;
  const int bm = blockIdx.x / tn, bn = blockIdx.x % tn;
  const int wm = wave & 1, wn = wave >> 1;
  const f32x4 z4 = {0.f, 0.f, 0.f, 0.f};
  f32x4 acc[4][4];
#pragma unroll
  for (int i = 0; i < 4; i++)
#pragma unroll
    for (int j = 0; j < 4; j++) acc[i][j] = z4;

  for (int k0 = 0; k0 < K; k0 += 64) {
#pragma unroll
    for (int is = 0; is < 4; is++) {
      int c = is * 4 + wave;
      int mb = c & 7, kb = c >> 3;
      async_ld16(A + (size_t)(bm * 128 + mb * 16 + m15) * K + k0 + kb * 32 + q8, smA + c * 512);
      async_ld16(B + (size_t)(bn * 128 + mb * 16 + m15) * K + k0 + kb * 32 + q8, smB + c * 512);
    }
    __syncthreads();
#pragma unroll
    for (int kk = 0; kk < 2; kk++) {
      short8 af[4], bf[4];
#pragma unroll
      for (int i = 0; i < 4; i++)
        af[i] = *(const short8*)(smA + (kk * 8 + wm * 4 + i) * 512 + lane * 8);
#pragma unroll
      for (int j = 0; j < 4; j++)
        bf[j] = *(const short8*)(smB + (kk * 8 + wn * 4 + j) * 512 + lane * 8);
#pragma unroll
      for (int i = 0; i < 4; i++)
#pragma unroll
        for (int j = 0; j < 4; j++)
          acc[i][j] = __builtin_amdgcn_mfma_f32_16x16x32_bf16(af[i], bf[j], acc[i][j], 0, 0, 0);
    }
    __syncthreads();
  }
#pragma unroll
  for (int j = 0; j < 4; j++) {
    int col = bn * 128 + wn * 64 + j * 16 + m15;
    float bv = bias[col];
#pragma unroll
    for (int i = 0; i < 4; i++) {
      int row0 = bm * 128 + wm * 64 + i * 16 + ((lane >> 4) << 2);
#pragma unroll
      for (int r = 0; r < 4; r++) {
        float v = acc[i][j][r] + bv;
        int rr = row0 + r;
        if (MODE == 0) {
          Cf[(size_t)rr * N + col] = v;
        } else if (MODE == 1) {
          if (v < 0.f) v = 0.f;
          Cb[(size_t)rr * N + col] = f2b(v);
        } else {
          // gi16: [t][b][768], rr = b*512 + t
          Cb[((size_t)((rr & 511) * 32 + (rr >> 9))) * 768 + col] = f2b(v);
        }
      }
    }
  }
}

// ---------------- bidirectional GRU: 16 independent blocks, two-phase step ----
// Block: d = blk&1, bg = blk>>1 -> 4 batch rows [bg*4, bg*4+4). 1024 threads.
// Phase A: 16 waves, wave v owns gh cols [16v,16v+16) x 3 gates; m=16 MFMA tile
//   (rows 4..15 of h are permanently zero). Writes real rows 0..3 of gh to
//   smG[gate][row][256] (conflict-free). 24 fp8 MFMAs/wave, B-frags in regs.
// Phase B: dense 1 element/thread (row=tid>>8, col=tid&255): gi via register
//   loads (issued at step start), gates with rcp/exp intrinsics, h -> fp8 LDS
//   (hb, stride 272) + bf16 hcat16 (t-major). hprev stays in a register.
__global__ __launch_bounds__(1024) void k_gru(
    const long* __restrict__ w8,
    const float* __restrict__ bhh_f, const float* __restrict__ bhh_b,
    const short* __restrict__ gi16_f, const short* __restrict__ gi16_b,
    short* __restrict__ hcat16) {
  __shared__ char  hb[2][4352];        // fp8 h: [row16][272]
  __shared__ float smG[3][4][256];     // gh fp32, real rows only
  const int blk = blockIdx.x;
  const int d = blk & 1, bg = blk >> 1;
  const int tid = threadIdx.x, lane = tid & 63, v = tid >> 6;
  const int m15 = lane & 15, quad = lane >> 4, q8 = quad * 8;
  const int brow = tid >> 8, bcol = tid & 255;     // phase-B element
  const float* bhh = d ? bhh_b : bhh_f;
  const short* gi  = d ? gi16_b : gi16_f;

  // B fragments (fp8): wave v owns cols v*16..+16, 3 gates x 8 k-blocks.
  // Per-(d,v) stride = 3*8*64 = 1536 longs.  (R5 bug: used 192 -> wrong weights)
  long Bf[3][8];
  {
    const long* wp = w8 + (size_t)(d * 16 + v) * 1536;
#pragma unroll
    for (int g = 0; g < 3; g++)
#pragma unroll
      for (int kb = 0; kb < 8; kb++)
        Bf[g][kb] = wp[(g * 8 + kb) * 64 + lane];
  }
  float bh[3];
#pragma unroll
  for (int g = 0; g < 3; g++) bh[g] = bhh[g * 256 + bcol];

  // zero both h buffers (rows 4..15 stay zero forever)
  for (int i = tid; i < 2176; i += 1024) ((int*)hb)[i] = 0;

  const int t0 = d ? 511 : 0;
  const int tstep = d ? -1 : 1;
  // per-thread gi pointers for this element, advanced by +-32*768 per step
  const long gdelta = (long)tstep * 32 * 768;
  const short* gp0 = gi + ((size_t)t0 * 32 + bg * 4 + brow) * 768 + bcol;
  const short* gp1 = gp0 + 256;
  const short* gp2 = gp0 + 512;
  short* hout = hcat16 + ((size_t)t0 * 32 + bg * 4 + brow) * 512 + d * 256 + bcol;
  const long hdelta = (long)tstep * 32 * 512;

  float gic0 = b2f(*gp0), gic1 = b2f(*gp1), gic2 = b2f(*gp2);
  gp0 += gdelta; gp1 += gdelta; gp2 += gdelta;
  float hprev = 0.f;
  const f32x4 z4 = {0.f, 0.f, 0.f, 0.f};
  __syncthreads();   // hb zero visible

  for (int s = 0; s < 512; s++) {
    // issue next step's gi loads early (latency hides under phase A)
    short n0 = 0, n1 = 0, n2 = 0;
    if (s < 511) {
      n0 = *gp0; n1 = *gp1; n2 = *gp2;
      gp0 += gdelta; gp1 += gdelta; gp2 += gdelta;
    }
    // ---- phase A: gh = h[s] @ w_hh^T  (redundant m, cheap) ----
    const char* hs = hb[s & 1];
    f32x4 acc0 = z4, acc1 = z4, acc2 = z4;
#pragma unroll
    for (int kb = 0; kb < 8; kb++) {
      long a = *(const long*)(hs + m15 * 272 + kb * 32 + q8);
      acc0 = __builtin_amdgcn_mfma_f32_16x16x32_fp8_fp8(a, Bf[0][kb], acc0, 0, 0, 0);
      acc1 = __builtin_amdgcn_mfma_f32_16x16x32_fp8_fp8(a, Bf[1][kb], acc1, 0, 0, 0);
      acc2 = __builtin_amdgcn_mfma_f32_16x16x32_fp8_fp8(a, Bf[2][kb], acc2, 0, 0, 0);
    }
    if (quad == 0) {         // C-layout: rows 0..3 live in quad 0, col = m15
      int c = v * 16 + m15;
#pragma unroll
      for (int i = 0; i < 4; i++) {
        smG[0][i][c] = acc0[i];
        smG[1][i][c] = acc1[i];
        smG[2][i][c] = acc2[i];
      }
    }
    __syncthreads();
    // ---- phase B: dense gates, 1 element/thread ----
    float gr = smG[0][brow][bcol];
    float gz = smG[1][brow][bcol];
    float gn = smG[2][brow][bcol];
    float r = fast_sigmoid(gic0 + gr + bh[0]);
    float z = fast_sigmoid(gic1 + gz + bh[1]);
    float n = fast_tanh(gic2 + r * (gn + bh[2]));
    float h = (1.f - z) * n + z * hprev;
    hprev = h;
    // h -> fp8 LDS for next step's phase A
    int p8 = __builtin_amdgcn_cvt_pk_fp8_f32(h, h, 0, false);
    hb[(s + 1) & 1][brow * 272 + bcol] = (char)(p8 & 0xff);
    // bf16 output (t-major), running pointer
    *hout = f2b(h);
    hout += hdelta;
    gic0 = b2f(n0); gic1 = b2f(n1); gic2 = b2f(n2);
    __syncthreads();   // publishes hb[s+1], protects smG reuse
  }
}

// ---------------- residual + LayerNorm ----------------
// FIRST=1: residual read from bf16 hcat16 (GRU output); else fp32 hres.
template <int FIRST>
__global__ __launch_bounds__(256) void k_ln(const float* __restrict__ hinf,
    const float* __restrict__ ff, const float* __restrict__ gw,
    const float* __restrict__ bw, float* __restrict__ hout, short* __restrict__ h16) {
  int row = blockIdx.x * 4 + (threadIdx.x >> 6);
  int lane = threadIdx.x & 63;
  size_t base = (size_t)row * 512 + lane * 8;
  f32x4 x0, x1;
  if (FIRST) {
    short8 hv = *(const short8*)(h16 + base);
#pragma unroll
    for (int i = 0; i < 4; i++) { x0[i] = b2f(hv[i]); x1[i] = b2f(hv[4 + i]); }
  } else {
    x0 = *(const f32x4*)(hinf + base);
    x1 = *(const f32x4*)(hinf + base + 4);
  }
  f32x4 y0 = *(const f32x4*)(ff + base);
  f32x4 y1 = *(const f32x4*)(ff + base + 4);
  x0 += y0; x1 += y1;
  float s = x0[0] + x0[1] + x0[2] + x0[3] + x1[0] + x1[1] + x1[2] + x1[3];
#pragma unroll
  for (int off = 32; off >= 1; off >>= 1) s += __shfl_xor(s, off);
  float mu = s * (1.f / 512.f);
  float vv = 0.f;
#pragma unroll
  for (int i = 0; i < 4; i++) { float d0 = x0[i] - mu, d1 = x1[i] - mu; vv += d0 * d0 + d1 * d1; }
#pragma unroll
  for (int off = 32; off >= 1; off >>= 1) vv += __shfl_xor(vv, off);
  float rs = rsqrtf(vv * (1.f / 512.f) + 1e-5f);
  int e = lane * 8;
  f32x4 g0 = *(const f32x4*)(gw + e), g1 = *(const f32x4*)(gw + e + 4);
  f32x4 bb0 = *(const f32x4*)(bw + e), bb1 = *(const f32x4*)(bw + e + 4);
  f32x4 o0, o1; short8 ob;
#pragma unroll
  for (int i = 0; i < 4; i++) {
    float a = (x0[i] - mu) * rs * g0[i] + bb0[i];
    float b = (x1[i] - mu) * rs * g1[i] + bb1[i];
    o0[i] = a; o1[i] = b; ob[i] = f2b(a); ob[4 + i] = f2b(b);
  }
  *(f32x4*)(hout + base) = o0;
  *(f32x4*)(hout + base + 4) = o1;
  *(short8*)(h16 + base) = ob;
}

// ---------------- final FC (N=16), fp32 weights ----------------
__global__ __launch_bounds__(256) void k_fc(const float* __restrict__ h,
    const float* __restrict__ fcw, const float* __restrict__ bias,
    float* __restrict__ logits) {
  int row = blockIdx.x * 4 + (threadIdx.x >> 6);
  int lane = threadIdx.x & 63;
  int c = lane & 15, part = lane >> 4;
  const float* ph = h + (size_t)row * 512 + part * 128;
  const float* pw = fcw + (size_t)part * 128 * 16 + c;
  float acc = 0.f;
#pragma unroll 8
  for (int k = 0; k < 128; k += 4) {
    f32x4 hv = *(const f32x4*)(ph + k);
    acc += hv[0] * pw[(k) * 16] + hv[1] * pw[(k + 1) * 16]
         + hv[2] * pw[(k + 2) * 16] + hv[3] * pw[(k + 3) * 16];
  }
  acc += __shfl_xor(acc, 16);
  acc += __shfl_xor(acc, 32);
  if (part == 0) logits[(size_t)row * 16 + c] = acc + bias[c];
}

// ---------------- CRF Viterbi: 1 wave per batch element ----------------
// logits layout is t-major: [t][b][16] -> element t at lg[t*512 + cur].
__global__ __launch_bounds__(64) void k_crf(const float* __restrict__ logits,
    const int* __restrict__ y, const float* __restrict__ trans,
    float* __restrict__ out) {
  __shared__ float tr[16][16];
  __shared__ unsigned char bp[511][16];
  int b = blockIdx.x, lane = threadIdx.x;
  for (int i = lane; i < 256; i += 64) tr[i >> 4][i & 15] = trans[i];
  __syncthreads();
  int cur = lane & 15;
  const float* lg = logits + (size_t)b * 16;
  const int* yb = y + b * 512;
  float score = tr[1][cur] + lg[cur];
  float e_next = lg[512 + cur];
  int y_next = yb[1];
  for (int t = 1; t < 512; t++) {
    float e = e_next; int ym = y_next;
    if (t < 511) { e_next = lg[(t + 1) * 512 + cur]; y_next = yb[t + 1]; }
    float best = -3.4e38f; int arg = 0;
#pragma unroll
    for (int p = 0; p < 16; p++) {
      float cand = __shfl(score, p) + tr[p][cur];
      if (cand > best) { best = cand; arg = p; }
    }
    if (lane < 16) bp[t - 1][cur] = (unsigned char)arg;
    float ns = best + e;
    if (ym == 0) ns = score;
    score = ns;
  }
  score += tr[cur][2];
  float best = -3.4e38f; int argb = 0;
#pragma unroll
  for (int p = 0; p < 16; p++) {
    float sp = __shfl(score, p);
    if (sp > best) { best = sp; argb = p; }
  }
  __syncthreads();
  if (lane == 0) {
    out[b] = best;
    float* po = out + 32 + (size_t)b * 512;
    int tag = argb;
    po[511] = (float)tag;
    for (int t = 511; t >= 1; t--) {
      int prev = bp[t - 1][tag];
      if (yb[t] == 0) prev = tag;
      po[t - 1] = (float)prev;
      tag = prev;
    }
  }
}

// ---------------- host ----------------
extern "C" void kernel_launch(void* const* d_in, const int* in_sizes, int n_in,
                              void* d_out, int out_size, void* d_ws, size_t ws_size,
                              hipStream_t stream) {
  const int*   x      = (const int*)d_in[0];
  const int*   y      = (const int*)d_in[1];
  const float* embedW = (const float*)d_in[2];
  const float* w_ih_f = (const float*)d_in[3];
  const float* w_hh_f = (const float*)d_in[4];
  const float* b_ih_f = (const float*)d_in[5];
  const float* b_hh_f = (const float*)d_in[6];
  const float* w_ih_b = (const float*)d_in[7];
  const float* w_hh_b = (const float*)d_in[8];
  const float* b_ih_b = (const float*)d_in[9];
  const float* b_hh_b = (const float*)d_in[10];
  const float* ff_w1  = (const float*)d_in[11];
  const float* ff_b1  = (const float*)d_in[12];
  const float* ff_w2  = (const float*)d_in[13];
  const float* ff_b2  = (const float*)d_in[14];
  const float* ln_g   = (const float*)d_in[15];
  const float* ln_b   = (const float*)d_in[16];
  const float* fc_w   = (const float*)d_in[17];
  const float* fc_b   = (const float*)d_in[18];
  const float* trans  = (const float*)d_in[19];
  float* out = (float*)d_out;

  char* ws = (char*)d_ws;
  short* h0     = (short*)(ws + 0);                 // 16.78 MB bf16 (B,T,E)
  short* gi16_f = (short*)(ws + 16777216);          // 25.17 MB bf16 [t][b][768]
  short* gi16_b = (short*)(ws + 41943040);          // 25.17 MB
  short* mid    = (short*)(ws + 16777216);          // 67.1 MB bf16, overlays gi16 (dead after GRU)
  float* ffout  = (float*)(ws + 83886080);          // 33.55 MB fp32
  short* wihf16 = (short*)(ws + 117440512);         // bf16 (768,512)
  short* wihb16 = (short*)(ws + 118226944);
  long*  w8     = (long*) (ws + 119013376);         // fp8 frags, 786432 B
  short* w1t    = (short*)(ws + 119799808);         // bf16 (4 x 2048x512)
  short* w2t    = (short*)(ws + 128188416);         // bf16 (4 x 512x2048)
  short* hcat16 = (short*)(ws + 136577024);         // bf16 [t][b][512]
  float* hres   = (float*)(ws + 153354240);         // fp32 residual [t][b][512]
  float* logits = (float*)(ws + 186908672);         // fp32 [t][b][16]

  k_embed<<<4096, 256, 0, stream>>>(x, embedW, h0);
  k_cvt2<<<768, 256, 0, stream>>>(w_ih_f, w_ih_b, wihf16, wihb16);
  k_w8<<<192, 256, 0, stream>>>(w_hh_f, w_hh_b, w8);
  k_transcvt<<<4096, 256, 0, stream>>>(ff_w1, w1t, 512, 2048);
  k_transcvt<<<4096, 256, 0, stream>>>(ff_w2, w2t, 2048, 512);

  k_gemm<2><<<768, 256, 0, stream>>>(h0, wihf16, b_ih_f, nullptr, gi16_f, 16384, 768, 512);
  k_gemm<2><<<768, 256, 0, stream>>>(h0, wihb16, b_ih_b, nullptr, gi16_b, 16384, 768, 512);

  k_gru<<<16, 1024, 0, stream>>>(w8, b_hh_f, b_hh_b, gi16_f, gi16_b, hcat16);

  for (int i = 0; i < 4; i++) {
    k_gemm<1><<<2048, 256, 0, stream>>>(hcat16, w1t + (size_t)i * 1048576, ff_b1 + i * 2048,
                                        nullptr, mid, 16384, 2048, 512);
    k_gemm<0><<<512, 256, 0, stream>>>(mid, w2t + (size_t)i * 1048576, ff_b2 + i * 512,
                                       ffout, nullptr, 16384, 512, 2048);
    if (i == 0)
      k_ln<1><<<4096, 256, 0, stream>>>(nullptr, ffout, ln_g, ln_b, hres, hcat16);
    else
      k_ln<0><<<4096, 256, 0, stream>>>(hres, ffout, ln_g + i * 512, ln_b + i * 512, hres, hcat16);
  }
  k_fc<<<4096, 256, 0, stream>>>(hres, fc_w, fc_b, logits);
  k_crf<<<32, 64, 0, stream>>>(logits, y, trans, out);
}

// Round 7
// 1778.546 us; speedup vs baseline: 4.3175x; 1.0300x over previous
//
#include <hip/hip_runtime.h>

#define DEV __device__ __forceinline__

using short8 = __attribute__((ext_vector_type(8))) short;
using f32x4  = __attribute__((ext_vector_type(4))) float;

DEV float b2f(short s) {
  union { unsigned u; float f; } c;
  c.u = ((unsigned)(unsigned short)s) << 16;
  return c.f;
}
DEV short f2b(float f) {
  union { float f; unsigned u; } c; c.f = f;
  unsigned u = c.u + 0x7fffu + ((c.u >> 16) & 1u);
  return (short)(u >> 16);
}
DEV float fast_sigmoid(float x) {   // rcp+exp: ~20 cyc vs ~90 for fp32 divide
  return __builtin_amdgcn_rcpf(1.f + __expf(-x));
}
DEV float fast_tanh(float x) {      // 1 - 2/(e^2x+1); saturates correctly at +-inf
  return 1.f - 2.f * __builtin_amdgcn_rcpf(1.f + __expf(2.f * x));
}
// async global->LDS, 16B per lane. LDS dest = uniform base + lane*16.
DEV void async_ld16(const void* g, void* lds) {
  __builtin_amdgcn_global_load_lds(
      (const __attribute__((address_space(1))) void*)(unsigned long long)g,
      (__attribute__((address_space(3))) void*)(unsigned)(unsigned long long)lds,
      16, 0, 0);
}

// ---------------- fp32 -> bf16 convert: w_ih_f, w_ih_b ----------------
__global__ __launch_bounds__(256) void k_cvt2(const float* __restrict__ a, const float* __restrict__ b,
                                              short* __restrict__ oa, short* __restrict__ ob) {
  int blk = blockIdx.x;
  const float* in; short* out; int base;
  if (blk < 384) { in = a; out = oa; base = blk; }
  else           { in = b; out = ob; base = blk - 384; }
  int i = base * 256 + threadIdx.x;
  f32x4 v = *(const f32x4*)(in + (size_t)i * 4);
  short4 o;
#pragma unroll
  for (int j = 0; j < 4; j++) ((short*)&o)[j] = f2b(v[j]);
  *(short4*)(out + (size_t)i * 4) = o;
}

// ---------------- w_hh fp32 -> fp8 e4m3 B-fragments ----------------
// out[d][v(16)][g(3)][kb(8)][lane(64)] : 8 bytes = B[n=lane&15][k=(lane>>4)*8+j]
__global__ __launch_bounds__(256) void k_w8(const float* __restrict__ wf,
                                            const float* __restrict__ wb,
                                            long* __restrict__ out) {
  int flat = blockIdx.x * 256 + threadIdx.x;   // 49152 total
  int lane = flat & 63;
  int r1 = flat >> 6;
  int kb = r1 & 7;
  int r2 = r1 >> 3;
  int g = r2 % 3;
  int r3 = r2 / 3;
  int v = r3 & 15;
  int d = r3 >> 4;
  const float* w = d ? wb : wf;
  int row = g * 256 + v * 16 + (lane & 15);
  int k0 = kb * 32 + (lane >> 4) * 8;
  const float* p = w + (size_t)row * 256 + k0;
  f32x4 f0 = *(const f32x4*)(p);
  f32x4 f1 = *(const f32x4*)(p + 4);
  int u0 = __builtin_amdgcn_cvt_pk_fp8_f32(f0[0], f0[1], 0, false);
  u0 = __builtin_amdgcn_cvt_pk_fp8_f32(f0[2], f0[3], u0, true);
  int u1 = __builtin_amdgcn_cvt_pk_fp8_f32(f1[0], f1[1], 0, false);
  u1 = __builtin_amdgcn_cvt_pk_fp8_f32(f1[2], f1[3], u1, true);
  out[flat] = ((long)(unsigned)u1 << 32) | (unsigned)u0;
}

// ---------------- embed + positional encoding (fp32 W -> bf16 h0) ----------------
__global__ __launch_bounds__(256) void k_embed(const int* __restrict__ x,
                                               const float* __restrict__ W,
                                               short* __restrict__ h0) {
  int flat = blockIdx.x * 256 + threadIdx.x;   // 0 .. 1048575 (B*T*E/8)
  int row  = flat >> 6;                        // b*T + t
  int e0   = (flat & 63) << 3;
  int tok  = x[row];
  int t    = row & 511;
  const float* wp = W + (size_t)tok * 512 + e0;
  float v[8];
  *(f32x4*)v       = *(const f32x4*)(wp);
  *(f32x4*)(v + 4) = *(const f32x4*)(wp + 4);
  short8 o;
#pragma unroll
  for (int i = 0; i < 8; i += 2) {
    float f = expf(-9.210340371976184f * (float)(e0 + i) * (1.f / 512.f));
    float ang = (float)t * f;
    o[i]     = f2b(v[i]     + sinf(ang));
    o[i + 1] = f2b(v[i + 1] + cosf(ang));
  }
  *(short8*)(h0 + (size_t)flat * 8) = o;
}

// ---------------- fp32 (R,C) -> bf16 (C,R) transpose+convert, 4 matrices ----------------
__global__ __launch_bounds__(256) void k_transcvt(const float* __restrict__ in0,
                                                  short* __restrict__ out0, int R, int C) {
  __shared__ float tile[32][33];
  int mat = blockIdx.x >> 10;
  const float* in = in0 + (size_t)mat * 1048576;
  short* out = out0 + (size_t)mat * 1048576;
  int blk = blockIdx.x & 1023;
  int ct = C >> 5;
  int bc = blk % ct, br = blk / ct;
  int r0 = br << 5, c0 = bc << 5;
  for (int i = threadIdx.x; i < 1024; i += 256) {
    int r = i >> 5, c = i & 31;
    tile[r][c] = in[(size_t)(r0 + r) * C + c0 + c];
  }
  __syncthreads();
  for (int i = threadIdx.x; i < 1024; i += 256) {
    int c = i >> 5, r = i & 31;
    out[(size_t)(c0 + c) * R + r0 + r] = f2b(tile[r][c]);
  }
}

// ---------------- 128x128 MFMA GEMM, A(M,K) bf16 * B(N,K) bf16 ----------------
// MODE 0: fp32 out + bias. MODE 1: bf16 out + bias + relu.
// MODE 2: bf16 out + bias, written to gi16 layout [t][b][768] (M rows are b*512+t).
template <int MODE>
__global__ __launch_bounds__(256) void k_gemm(const short* __restrict__ A,
    const short* __restrict__ B, const float* __restrict__ bias,
    float* __restrict__ Cf, short* __restrict__ Cb, int M, int N, int K) {
  __shared__ short smA[8192];
  __shared__ short smB[8192];
  const int tid = threadIdx.x, lane = tid & 63, wave = tid >> 6;
  const int m15 = lane & 15, q8 = (lane >> 4) << 3;
  const int tn = N >> 7;
  const int bm = blockIdx.x / tn, bn = blockIdx.x % tn;
  const int wm = wave & 1, wn = wave >> 1;
  const f32x4 z4 = {0.f, 0.f, 0.f, 0.f};
  f32x4 acc[4][4];
#pragma unroll
  for (int i = 0; i < 4; i++)
#pragma unroll
    for (int j = 0; j < 4; j++) acc[i][j] = z4;

  for (int k0 = 0; k0 < K; k0 += 64) {
#pragma unroll
    for (int is = 0; is < 4; is++) {
      int c = is * 4 + wave;
      int mb = c & 7, kb = c >> 3;
      async_ld16(A + (size_t)(bm * 128 + mb * 16 + m15) * K + k0 + kb * 32 + q8, smA + c * 512);
      async_ld16(B + (size_t)(bn * 128 + mb * 16 + m15) * K + k0 + kb * 32 + q8, smB + c * 512);
    }
    __syncthreads();
#pragma unroll
    for (int kk = 0; kk < 2; kk++) {
      short8 af[4], bf[4];
#pragma unroll
      for (int i = 0; i < 4; i++)
        af[i] = *(const short8*)(smA + (kk * 8 + wm * 4 + i) * 512 + lane * 8);
#pragma unroll
      for (int j = 0; j < 4; j++)
        bf[j] = *(const short8*)(smB + (kk * 8 + wn * 4 + j) * 512 + lane * 8);
#pragma unroll
      for (int i = 0; i < 4; i++)
#pragma unroll
        for (int j = 0; j < 4; j++)
          acc[i][j] = __builtin_amdgcn_mfma_f32_16x16x32_bf16(af[i], bf[j], acc[i][j], 0, 0, 0);
    }
    __syncthreads();
  }
#pragma unroll
  for (int j = 0; j < 4; j++) {
    int col = bn * 128 + wn * 64 + j * 16 + m15;
    float bv = bias[col];
#pragma unroll
    for (int i = 0; i < 4; i++) {
      int row0 = bm * 128 + wm * 64 + i * 16 + ((lane >> 4) << 2);
#pragma unroll
      for (int r = 0; r < 4; r++) {
        float v = acc[i][j][r] + bv;
        int rr = row0 + r;
        if (MODE == 0) {
          Cf[(size_t)rr * N + col] = v;
        } else if (MODE == 1) {
          if (v < 0.f) v = 0.f;
          Cb[(size_t)rr * N + col] = f2b(v);
        } else {
          // gi16: [t][b][768], rr = b*512 + t
          Cb[((size_t)((rr & 511) * 32 + (rr >> 9))) * 768 + col] = f2b(v);
        }
      }
    }
  }
}

// ---------------- bidirectional GRU v3: one barrier/step ----------------
// 16 independent blocks (d = blk&1, bg = blk>>1 -> 4 batch rows), 1024 thr.
// Wave v owns h cols [16v,16v+16). Phase A: 24 fp8 MFMAs (B-frags in regs,
// A from fp8 LDS hb). Gate exchange is WAVE-LOCAL: quad-0 lanes write the
// C-frags to smG[v][..], same wave reads smG[v][lane] — same-wave DS ops are
// in-order, no barrier. Phase B: 1 element/lane (row=quad, col=v*16+m15).
// The ONLY barrier protects the hb double buffer. Output h is buffered 8
// steps in registers and flushed every 8th step, so the barrier's implicit
// vmcnt(0) drain only pays for stores once per 8 steps.
__global__ __launch_bounds__(1024) void k_gru(
    const long* __restrict__ w8,
    const float* __restrict__ bhh_f, const float* __restrict__ bhh_b,
    const short* __restrict__ gi16_f, const short* __restrict__ gi16_b,
    short* __restrict__ hcat16) {
  __shared__ char  hb[2][4352];        // fp8 h: [row16][272]
  __shared__ float smG[16][200];       // wave-private exchange (192 used + pad)
  const int blk = blockIdx.x;
  const int d = blk & 1, bg = blk >> 1;
  const int tid = threadIdx.x, lane = tid & 63, v = tid >> 6;
  const int m15 = lane & 15, quad = lane >> 4, q8 = quad * 8;
  const int col = v * 16 + m15;        // this lane's h column
  const int brow = quad;               // this lane's local batch row (0..3)
  const float* bhh = d ? bhh_b : bhh_f;
  const short* gi  = d ? gi16_b : gi16_f;

  // B fragments (fp8): per-(d,v) stride = 3*8*64 = 1536 longs
  long Bf[3][8];
  {
    const long* wp = w8 + (size_t)(d * 16 + v) * 1536;
#pragma unroll
    for (int g = 0; g < 3; g++)
#pragma unroll
      for (int kb = 0; kb < 8; kb++)
        Bf[g][kb] = wp[(g * 8 + kb) * 64 + lane];
  }
  float bh[3];
#pragma unroll
  for (int g = 0; g < 3; g++) bh[g] = bhh[g * 256 + col];

  // zero both h buffers (rows 4..15 stay zero forever)
  for (int i = tid; i < 2176; i += 1024) ((int*)hb)[i] = 0;

  const int t0 = d ? 511 : 0;
  const long gdelta = (long)(d ? -1 : 1) * 32 * 768;
  const long hdelta = (long)(d ? -1 : 1) * 32 * 512;
  const short* gp0 = gi + ((size_t)t0 * 32 + bg * 4 + brow) * 768 + col;
  const short* gp1 = gp0 + 256;
  const short* gp2 = gp0 + 512;
  short* hflush = hcat16 + ((size_t)t0 * 32 + bg * 4 + brow) * 512 + d * 256 + col;

  float gic0 = b2f(*gp0), gic1 = b2f(*gp1), gic2 = b2f(*gp2);
  gp0 += gdelta; gp1 += gdelta; gp2 += gdelta;
  float hprev = 0.f;
  unsigned obuf[4] = {0u, 0u, 0u, 0u};
  const f32x4 z4 = {0.f, 0.f, 0.f, 0.f};
  __syncthreads();   // hb zero visible

  for (int s = 0; s < 512; s++) {
    // next step's gi loads (hide L2/HBM latency under phase A)
    short n0 = 0, n1 = 0, n2 = 0;
    if (s < 511) {
      n0 = *gp0; n1 = *gp1; n2 = *gp2;
      gp0 += gdelta; gp1 += gdelta; gp2 += gdelta;
    }
    // ---- phase A: gh = h[s] @ w_hh^T ----
    const char* hs = hb[s & 1];
    f32x4 acc0 = z4, acc1 = z4, acc2 = z4;
#pragma unroll
    for (int kb = 0; kb < 8; kb++) {
      long a = *(const long*)(hs + m15 * 272 + kb * 32 + q8);
      acc0 = __builtin_amdgcn_mfma_f32_16x16x32_fp8_fp8(a, Bf[0][kb], acc0, 0, 0, 0);
      acc1 = __builtin_amdgcn_mfma_f32_16x16x32_fp8_fp8(a, Bf[1][kb], acc1, 0, 0, 0);
      acc2 = __builtin_amdgcn_mfma_f32_16x16x32_fp8_fp8(a, Bf[2][kb], acc2, 0, 0, 0);
    }
    // ---- wave-local gate exchange (no barrier; same-wave DS is in-order) ----
    if (quad == 0) {     // C-layout rows 0..3 live in quad 0, col = m15
#pragma unroll
      for (int i = 0; i < 4; i++) {
        smG[v][i * 16 + m15]       = acc0[i];
        smG[v][64 + i * 16 + m15]  = acc1[i];
        smG[v][128 + i * 16 + m15] = acc2[i];
      }
    }
    float gr = smG[v][lane];          // row=quad, c=m15 -> quad*16+m15 = lane
    float gz = smG[v][64 + lane];
    float gn = smG[v][128 + lane];
    // ---- phase B: gates, 1 element/lane ----
    float r = fast_sigmoid(gic0 + gr + bh[0]);
    float z = fast_sigmoid(gic1 + gz + bh[1]);
    float n = fast_tanh(gic2 + r * (gn + bh[2]));
    float h = (1.f - z) * n + z * hprev;
    hprev = h;
    // h -> fp8 LDS for next step
    int p8 = __builtin_amdgcn_cvt_pk_fp8_f32(h, h, 0, false);
    hb[(s + 1) & 1][brow * 272 + col] = (char)(p8 & 0xff);
    // buffer bf16 output; flush every 8 steps (amortizes barrier store-drain)
    unsigned hb16 = (unsigned)(unsigned short)f2b(h);
    int idx = s & 7;
    if ((idx & 1) == 0) obuf[idx >> 1] = hb16;
    else                obuf[idx >> 1] |= hb16 << 16;
    if (idx == 7) {
      short* p = hflush;
#pragma unroll
      for (int k = 0; k < 8; k++) {
        *p = (short)(obuf[k >> 1] >> ((k & 1) * 16));
        p += hdelta;
      }
      hflush += 8 * hdelta;
    }
    gic0 = b2f(n0); gic1 = b2f(n1); gic2 = b2f(n2);
    __syncthreads();   // the one barrier: publishes hb[s+1]
  }
}

// ---------------- residual + LayerNorm ----------------
// FIRST=1: residual read from bf16 hcat16 (GRU output); else fp32 hres.
template <int FIRST>
__global__ __launch_bounds__(256) void k_ln(const float* __restrict__ hinf,
    const float* __restrict__ ff, const float* __restrict__ gw,
    const float* __restrict__ bw, float* __restrict__ hout, short* __restrict__ h16) {
  int row = blockIdx.x * 4 + (threadIdx.x >> 6);
  int lane = threadIdx.x & 63;
  size_t base = (size_t)row * 512 + lane * 8;
  f32x4 x0, x1;
  if (FIRST) {
    short8 hv = *(const short8*)(h16 + base);
#pragma unroll
    for (int i = 0; i < 4; i++) { x0[i] = b2f(hv[i]); x1[i] = b2f(hv[4 + i]); }
  } else {
    x0 = *(const f32x4*)(hinf + base);
    x1 = *(const f32x4*)(hinf + base + 4);
  }
  f32x4 y0 = *(const f32x4*)(ff + base);
  f32x4 y1 = *(const f32x4*)(ff + base + 4);
  x0 += y0; x1 += y1;
  float s = x0[0] + x0[1] + x0[2] + x0[3] + x1[0] + x1[1] + x1[2] + x1[3];
#pragma unroll
  for (int off = 32; off >= 1; off >>= 1) s += __shfl_xor(s, off);
  float mu = s * (1.f / 512.f);
  float vv = 0.f;
#pragma unroll
  for (int i = 0; i < 4; i++) { float d0 = x0[i] - mu, d1 = x1[i] - mu; vv += d0 * d0 + d1 * d1; }
#pragma unroll
  for (int off = 32; off >= 1; off >>= 1) vv += __shfl_xor(vv, off);
  float rs = rsqrtf(vv * (1.f / 512.f) + 1e-5f);
  int e = lane * 8;
  f32x4 g0 = *(const f32x4*)(gw + e), g1 = *(const f32x4*)(gw + e + 4);
  f32x4 bb0 = *(const f32x4*)(bw + e), bb1 = *(const f32x4*)(bw + e + 4);
  f32x4 o0, o1; short8 ob;
#pragma unroll
  for (int i = 0; i < 4; i++) {
    float a = (x0[i] - mu) * rs * g0[i] + bb0[i];
    float b = (x1[i] - mu) * rs * g1[i] + bb1[i];
    o0[i] = a; o1[i] = b; ob[i] = f2b(a); ob[4 + i] = f2b(b);
  }
  *(f32x4*)(hout + base) = o0;
  *(f32x4*)(hout + base + 4) = o1;
  *(short8*)(h16 + base) = ob;
}

// ---------------- final FC (N=16), fp32 weights ----------------
__global__ __launch_bounds__(256) void k_fc(const float* __restrict__ h,
    const float* __restrict__ fcw, const float* __restrict__ bias,
    float* __restrict__ logits) {
  int row = blockIdx.x * 4 + (threadIdx.x >> 6);
  int lane = threadIdx.x & 63;
  int c = lane & 15, part = lane >> 4;
  const float* ph = h + (size_t)row * 512 + part * 128;
  const float* pw = fcw + (size_t)part * 128 * 16 + c;
  float acc = 0.f;
#pragma unroll 8
  for (int k = 0; k < 128; k += 4) {
    f32x4 hv = *(const f32x4*)(ph + k);
    acc += hv[0] * pw[(k) * 16] + hv[1] * pw[(k + 1) * 16]
         + hv[2] * pw[(k + 2) * 16] + hv[3] * pw[(k + 3) * 16];
  }
  acc += __shfl_xor(acc, 16);
  acc += __shfl_xor(acc, 32);
  if (part == 0) logits[(size_t)row * 16 + c] = acc + bias[c];
}

// ---------------- CRF Viterbi: 1 wave per batch element ----------------
// logits layout is t-major: [t][b][16] -> element t at lg[t*512 + cur].
__global__ __launch_bounds__(64) void k_crf(const float* __restrict__ logits,
    const int* __restrict__ y, const float* __restrict__ trans,
    float* __restrict__ out) {
  __shared__ float tr[16][16];
  __shared__ unsigned char bp[511][16];
  int b = blockIdx.x, lane = threadIdx.x;
  for (int i = lane; i < 256; i += 64) tr[i >> 4][i & 15] = trans[i];
  __syncthreads();
  int cur = lane & 15;
  const float* lg = logits + (size_t)b * 16;
  const int* yb = y + b * 512;
  float score = tr[1][cur] + lg[cur];
  float e_next = lg[512 + cur];
  int y_next = yb[1];
  for (int t = 1; t < 512; t++) {
    float e = e_next; int ym = y_next;
    if (t < 511) { e_next = lg[(t + 1) * 512 + cur]; y_next = yb[t + 1]; }
    float best = -3.4e38f; int arg = 0;
#pragma unroll
    for (int p = 0; p < 16; p++) {
      float cand = __shfl(score, p) + tr[p][cur];
      if (cand > best) { best = cand; arg = p; }
    }
    if (lane < 16) bp[t - 1][cur] = (unsigned char)arg;
    float ns = best + e;
    if (ym == 0) ns = score;
    score = ns;
  }
  score += tr[cur][2];
  float best = -3.4e38f; int argb = 0;
#pragma unroll
  for (int p = 0; p < 16; p++) {
    float sp = __shfl(score, p);
    if (sp > best) { best = sp; argb = p; }
  }
  __syncthreads();
  if (lane == 0) {
    out[b] = best;
    float* po = out + 32 + (size_t)b * 512;
    int tag = argb;
    po[511] = (float)tag;
    for (int t = 511; t >= 1; t--) {
      int prev = bp[t - 1][tag];
      if (yb[t] == 0) prev = tag;
      po[t - 1] = (float)prev;
      tag = prev;
    }
  }
}

// ---------------- host ----------------
extern "C" void kernel_launch(void* const* d_in, const int* in_sizes, int n_in,
                              void* d_out, int out_size, void* d_ws, size_t ws_size,
                              hipStream_t stream) {
  const int*   x      = (const int*)d_in[0];
  const int*   y      = (const int*)d_in[1];
  const float* embedW = (const float*)d_in[2];
  const float* w_ih_f = (const float*)d_in[3];
  const float* w_hh_f = (const float*)d_in[4];
  const float* b_ih_f = (const float*)d_in[5];
  const float* b_hh_f = (const float*)d_in[6];
  const float* w_ih_b = (const float*)d_in[7];
  const float* w_hh_b = (const float*)d_in[8];
  const float* b_ih_b = (const float*)d_in[9];
  const float* b_hh_b = (const float*)d_in[10];
  const float* ff_w1  = (const float*)d_in[11];
  const float* ff_b1  = (const float*)d_in[12];
  const float* ff_w2  = (const float*)d_in[13];
  const float* ff_b2  = (const float*)d_in[14];
  const float* ln_g   = (const float*)d_in[15];
  const float* ln_b   = (const float*)d_in[16];
  const float* fc_w   = (const float*)d_in[17];
  const float* fc_b   = (const float*)d_in[18];
  const float* trans  = (const float*)d_in[19];
  float* out = (float*)d_out;

  char* ws = (char*)d_ws;
  short* h0     = (short*)(ws + 0);                 // 16.78 MB bf16 (B,T,E)
  short* gi16_f = (short*)(ws + 16777216);          // 25.17 MB bf16 [t][b][768]
  short* gi16_b = (short*)(ws + 41943040);          // 25.17 MB
  short* mid    = (short*)(ws + 16777216);          // 67.1 MB bf16, overlays gi16 (dead after GRU)
  float* ffout  = (float*)(ws + 83886080);          // 33.55 MB fp32
  short* wihf16 = (short*)(ws + 117440512);         // bf16 (768,512)
  short* wihb16 = (short*)(ws + 118226944);
  long*  w8     = (long*) (ws + 119013376);         // fp8 frags, 786432 B
  short* w1t    = (short*)(ws + 119799808);         // bf16 (4 x 2048x512)
  short* w2t    = (short*)(ws + 128188416);         // bf16 (4 x 512x2048)
  short* hcat16 = (short*)(ws + 136577024);         // bf16 [t][b][512]
  float* hres   = (float*)(ws + 153354240);         // fp32 residual [t][b][512]
  float* logits = (float*)(ws + 186908672);         // fp32 [t][b][16]

  k_embed<<<4096, 256, 0, stream>>>(x, embedW, h0);
  k_cvt2<<<768, 256, 0, stream>>>(w_ih_f, w_ih_b, wihf16, wihb16);
  k_w8<<<192, 256, 0, stream>>>(w_hh_f, w_hh_b, w8);
  k_transcvt<<<4096, 256, 0, stream>>>(ff_w1, w1t, 512, 2048);
  k_transcvt<<<4096, 256, 0, stream>>>(ff_w2, w2t, 2048, 512);

  k_gemm<2><<<768, 256, 0, stream>>>(h0, wihf16, b_ih_f, nullptr, gi16_f, 16384, 768, 512);
  k_gemm<2><<<768, 256, 0, stream>>>(h0, wihb16, b_ih_b, nullptr, gi16_b, 16384, 768, 512);

  k_gru<<<16, 1024, 0, stream>>>(w8, b_hh_f, b_hh_b, gi16_f, gi16_b, hcat16);

  for (int i = 0; i < 4; i++) {
    k_gemm<1><<<2048, 256, 0, stream>>>(hcat16, w1t + (size_t)i * 1048576, ff_b1 + i * 2048,
                                        nullptr, mid, 16384, 2048, 512);
    k_gemm<0><<<512, 256, 0, stream>>>(mid, w2t + (size_t)i * 1048576, ff_b2 + i * 512,
                                       ffout, nullptr, 16384, 512, 2048);
    if (i == 0)
      k_ln<1><<<4096, 256, 0, stream>>>(nullptr, ffout, ln_g, ln_b, hres, hcat16);
    else
      k_ln<0><<<4096, 256, 0, stream>>>(hres, ffout, ln_g + i * 512, ln_b + i * 512, hres, hcat16);
  }
  k_fc<<<4096, 256, 0, stream>>>(hres, fc_w, fc_b, logits);
  k_crf<<<32, 64, 0, stream>>>(logits, y, trans, out);
}